// Round 1
// baseline (8238.602 us; speedup 1.0000x reference)
//
#include <hip/hip_runtime.h>
#include <math.h>

#define NB 8
#define NH 8
#define NS 1024
#define NE 512
#define NA 64
#define NBH (NB*NH)

static __device__ __forceinline__ float dot4(float4 a, float4 b) {
    return fmaf(a.x, b.x, fmaf(a.y, b.y, fmaf(a.z, b.z, a.w * b.w)));
}

// ---------------- K1: embedding gather + LayerNorm -> h [B*S, E] ----------------
__global__ __launch_bounds__(256) void k_embed_ln(
    const int* __restrict__ x, const float* __restrict__ emb,
    const float* __restrict__ gamma, const float* __restrict__ beta,
    float* __restrict__ h)
{
    int row = blockIdx.x;                 // b*S + s
    int tok = x[row];
    const float* e = emb + (size_t)tok * NE;
    int t = threadIdx.x;
    float v0 = e[t], v1 = e[t + 256];
    float sum = v0 + v1, ssq = v0 * v0 + v1 * v1;
    #pragma unroll
    for (int o = 32; o > 0; o >>= 1) {
        sum += __shfl_xor(sum, o);
        ssq += __shfl_xor(ssq, o);
    }
    __shared__ float wsum[4], wssq[4];
    __shared__ float mu_s, rstd_s;
    int wid = t >> 6;
    if ((t & 63) == 0) { wsum[wid] = sum; wssq[wid] = ssq; }
    __syncthreads();
    if (t == 0) {
        float S1 = wsum[0] + wsum[1] + wsum[2] + wsum[3];
        float S2 = wssq[0] + wssq[1] + wssq[2] + wssq[3];
        float mu = S1 / NE;
        float var = S2 / NE - mu * mu;
        mu_s = mu;
        rstd_s = rsqrtf(var + 1e-5f);
    }
    __syncthreads();
    float mu = mu_s, rstd = rstd_s;
    float* hr = h + (size_t)row * NE;
    hr[t]       = (v0 - mu) * rstd * gamma[t]       + beta[t];
    hr[t + 256] = (v1 - mu) * rstd * gamma[t + 256] + beta[t + 256];
}

// ---------------- K2: Q/K projections -> q,k [BH, S, A] ----------------
// block = (bh, s-tile of 8); 256 threads = 64 a x 4 s-groups (2 s each)
__global__ __launch_bounds__(256) void k_qk(
    const float* __restrict__ h, const float* __restrict__ Wq,
    const float* __restrict__ Wk, float* __restrict__ q, float* __restrict__ k)
{
    int blk = blockIdx.x;
    int st = blk & (NS / 8 - 1);          // 0..127
    int bh = blk >> 7;                    // 0..63
    int b = bh >> 3, hh = bh & 7;
    int s0 = st * 8;
    __shared__ float hs[8 * NE];          // 16 KiB
    {
        const float4* src4 = (const float4*)(h + ((size_t)(b * NS + s0)) * NE);
        float4* dst4 = (float4*)hs;
        #pragma unroll
        for (int i = threadIdx.x; i < 8 * NE / 4; i += 256) dst4[i] = src4[i];
    }
    __syncthreads();
    int a = threadIdx.x & 63;
    int g = threadIdx.x >> 6;             // 0..3
    const float4* wq4 = (const float4*)(Wq + ((size_t)(hh * NA + a)) * NE);
    const float4* wk4 = (const float4*)(Wk + ((size_t)(hh * NA + a)) * NE);
    float accq[2] = {0.f, 0.f}, acck[2] = {0.f, 0.f};
    for (int c = 0; c < NE / 4; ++c) {
        float4 wqv = wq4[c], wkv = wk4[c];
        #pragma unroll
        for (int j = 0; j < 2; ++j) {
            int sl = g + 4 * j;
            float4 hv = ((const float4*)(hs + sl * NE))[c];
            accq[j] += dot4(wqv, hv);
            acck[j] += dot4(wkv, hv);
        }
    }
    #pragma unroll
    for (int j = 0; j < 2; ++j) {
        int s = s0 + g + 4 * j;
        q[((size_t)bh * NS + s) * NA + a] = accq[j];
        k[((size_t)bh * NS + s) * NA + a] = acck[j];
    }
}

// ---------------- K3: V projection -> v [BH, S, E] ----------------
// block = (bh, t-tile of 16); thread owns e'=tid and tid+256
__global__ __launch_bounds__(256, 2) void k_v(
    const float* __restrict__ h, const float* __restrict__ Wv,
    float* __restrict__ v)
{
    int blk = blockIdx.x;
    int tt = blk & 63;                    // 0..63 (S/16)
    int bh = blk >> 6;
    int b = bh >> 3, hh = bh & 7;
    int t0 = tt * 16;
    __shared__ float ht[16 * NE];         // 32 KiB
    {
        const float4* src4 = (const float4*)(h + ((size_t)(b * NS + t0)) * NE);
        float4* dst4 = (float4*)ht;
        #pragma unroll
        for (int i = threadIdx.x; i < 16 * NE / 4; i += 256) dst4[i] = src4[i];
    }
    __syncthreads();
    int e0 = threadIdx.x, e1 = threadIdx.x + 256;
    const float4* w0 = (const float4*)(Wv + ((size_t)(hh * NE + e0)) * NE);
    const float4* w1 = (const float4*)(Wv + ((size_t)(hh * NE + e1)) * NE);
    float acc0[16], acc1[16];
    #pragma unroll
    for (int t = 0; t < 16; ++t) { acc0[t] = 0.f; acc1[t] = 0.f; }
    for (int c = 0; c < NE / 4; ++c) {
        float4 a0 = w0[c], a1 = w1[c];
        #pragma unroll
        for (int t = 0; t < 16; ++t) {
            float4 hv = ((const float4*)(ht + t * NE))[c];   // broadcast
            acc0[t] += dot4(a0, hv);
            acc1[t] += dot4(a1, hv);
        }
    }
    #pragma unroll
    for (int t = 0; t < 16; ++t) {
        v[((size_t)bh * NS + t0 + t) * NE + e0] = acc0[t];
        v[((size_t)bh * NS + t0 + t) * NE + e1] = acc1[t];
    }
}

// ---------------- K4: per-row min/max of raw QK^T dots ----------------
// block = (bh, s-tile 64); 4 waves split the t-range of each staged k tile
__global__ __launch_bounds__(256) void k_minmax(
    const float* __restrict__ q, const float* __restrict__ k,
    float* __restrict__ rmn, float* __restrict__ rmx)
{
    int blk = blockIdx.x;
    int st = blk & 15;
    int bh = blk >> 4;
    int s0 = st * 64;
    int lane = threadIdx.x & 63;
    int w = threadIdx.x >> 6;
    float4 qf[16];
    {
        const float4* qsrc = (const float4*)(q + ((size_t)bh * NS + s0 + lane) * NA);
        #pragma unroll
        for (int c = 0; c < 16; ++c) qf[c] = qsrc[c];
    }
    __shared__ float kt[64 * NA];         // 16 KiB
    float mn = 1e30f, mx = -1e30f;
    for (int t0 = 0; t0 < NS; t0 += 64) {
        __syncthreads();
        {
            const float4* ksrc = (const float4*)(k + ((size_t)bh * NS + t0) * NA);
            float4* kd = (float4*)kt;
            #pragma unroll
            for (int i = threadIdx.x; i < 64 * NA / 4; i += 256) kd[i] = ksrc[i];
        }
        __syncthreads();
        #pragma unroll
        for (int i = 0; i < 16; ++i) {
            const float4* kr = (const float4*)(kt + (w * 16 + i) * NA); // broadcast
            float acc = 0.f;
            #pragma unroll
            for (int c = 0; c < 16; ++c) acc += dot4(qf[c], kr[c]);
            mn = fminf(mn, acc);
            mx = fmaxf(mx, acc);
        }
    }
    __shared__ float smn[4][64], smx[4][64];
    smn[w][lane] = mn; smx[w][lane] = mx;
    __syncthreads();
    if (w == 0) {
        float m1 = fminf(fminf(smn[0][lane], smn[1][lane]), fminf(smn[2][lane], smn[3][lane]));
        float m2 = fmaxf(fmaxf(smx[0][lane], smx[1][lane]), fmaxf(smx[2][lane], smx[3][lane]));
        rmn[(size_t)bh * NS + s0 + lane] = m1;
        rmx[(size_t)bh * NS + s0 + lane] = m2;
    }
}

// ---------------- K5: recompute scores, sigmoid weights, accumulate PV ----------------
// block = (bh, s-tile 32); phase A: 1024 dots -> weights in LDS; phase B: w @ v
__global__ __launch_bounds__(256, 2) void k_attn(
    const float* __restrict__ q, const float* __restrict__ k,
    const float* __restrict__ v, const float* __restrict__ rmn,
    const float* __restrict__ rmx, float* __restrict__ out)
{
    int blk = blockIdx.x;
    int st = blk & 31;
    int bh = blk >> 5;
    int s0 = st * 32;
    int tid = threadIdx.x;
    int sl = tid & 31;
    int tg = tid >> 5;                    // 0..7
    float4 qf[16];
    {
        const float4* qsrc = (const float4*)(q + ((size_t)bh * NS + s0 + sl) * NA);
        #pragma unroll
        for (int c = 0; c < 16; ++c) qf[c] = qsrc[c];
    }
    float mn = rmn[(size_t)bh * NS + s0 + sl];
    float inv = 1.0f / (rmx[(size_t)bh * NS + s0 + sl] - mn);
    __shared__ __align__(16) float kt[32 * NA];    // 8 KiB
    __shared__ __align__(16) float wt[32 * 36];    // 4.5 KiB, pad 36
    float acc0[32], acc1[32];
    #pragma unroll
    for (int i = 0; i < 32; ++i) { acc0[i] = 0.f; acc1[i] = 0.f; }
    int e0 = tid, e1 = tid + 256;
    for (int t0 = 0; t0 < NS; t0 += 32) {
        __syncthreads();    // prev iter done reading kt/wt
        {
            const float4* ksrc = (const float4*)(k + ((size_t)bh * NS + t0) * NA);
            float4* kd = (float4*)kt;
            #pragma unroll
            for (int i = tid; i < 32 * NA / 4; i += 256) kd[i] = ksrc[i];
        }
        __syncthreads();    // kt ready
        // phase A: scores -> weights
        #pragma unroll
        for (int j = 0; j < 4; ++j) {
            int tl = tg * 4 + j;
            const float4* kr = (const float4*)(kt + tl * NA);
            float acc = 0.f;
            #pragma unroll
            for (int c = 0; c < 16; ++c) acc += dot4(qf[c], kr[c]);
            float sn = (acc - mn) * inv;             // scale cancels exactly
            wt[sl * 36 + tl] = 1.0f / (1.0f + __expf(5.0f - 10.0f * sn));
        }
        __syncthreads();    // wt ready
        // phase B: out += w @ v
        #pragma unroll
        for (int t4 = 0; t4 < 8; ++t4) {
            float v0[4], v1[4];
            #pragma unroll
            for (int j = 0; j < 4; ++j) {
                const float* vr = v + ((size_t)bh * NS + t0 + t4 * 4 + j) * NE;
                v0[j] = vr[e0];
                v1[j] = vr[e1];
            }
            #pragma unroll
            for (int s = 0; s < 32; ++s) {
                float4 wv = *((const float4*)(wt + s * 36 + t4 * 4)); // broadcast
                acc0[s] = fmaf(wv.x, v0[0], acc0[s]);
                acc0[s] = fmaf(wv.y, v0[1], acc0[s]);
                acc0[s] = fmaf(wv.z, v0[2], acc0[s]);
                acc0[s] = fmaf(wv.w, v0[3], acc0[s]);
                acc1[s] = fmaf(wv.x, v1[0], acc1[s]);
                acc1[s] = fmaf(wv.y, v1[1], acc1[s]);
                acc1[s] = fmaf(wv.z, v1[2], acc1[s]);
                acc1[s] = fmaf(wv.w, v1[3], acc1[s]);
            }
        }
    }
    #pragma unroll
    for (int s = 0; s < 32; ++s) {
        float* o = out + ((size_t)bh * NS + s0 + s) * NE;
        o[e0] = acc0[s];
        o[e1] = acc1[s];
    }
}

extern "C" void kernel_launch(void* const* d_in, const int* in_sizes, int n_in,
                              void* d_out, int out_size, void* d_ws, size_t ws_size,
                              hipStream_t stream) {
    const int*   x     = (const int*)d_in[0];
    const float* emb   = (const float*)d_in[1];
    const float* gamma = (const float*)d_in[2];
    const float* beta  = (const float*)d_in[3];
    const float* Wq    = (const float*)d_in[4];
    const float* Wk    = (const float*)d_in[5];
    const float* Wv    = (const float*)d_in[6];
    float* out = (float*)d_out;

    float* ws = (float*)d_ws;
    const size_t n_h = (size_t)NB * NS * NE;        // 4,194,304
    const size_t n_qk = (size_t)NBH * NS * NA;      // 4,194,304
    const size_t n_v = (size_t)NBH * NS * NE;       // 33,554,432
    float* h   = ws;
    float* q   = h + n_h;
    float* k   = q + n_qk;
    float* v   = k + n_qk;
    float* rmn = v + n_v;
    float* rmx = rmn + (size_t)NBH * NS;

    k_embed_ln<<<NB * NS, 256, 0, stream>>>(x, emb, gamma, beta, h);
    k_qk<<<NBH * (NS / 8), 256, 0, stream>>>(h, Wq, Wk, q, k);
    k_v<<<NBH * (NS / 16), 256, 0, stream>>>(h, Wv, v);
    k_minmax<<<NBH * (NS / 64), 256, 0, stream>>>(q, k, rmn, rmx);
    k_attn<<<NBH * (NS / 32), 256, 0, stream>>>(q, k, v, rmn, rmx, out);
}

// Round 2
// 619.569 us; speedup vs baseline: 13.2973x; 13.2973x over previous
//
#include <hip/hip_runtime.h>
#include <math.h>

#define NB 8
#define NH 8
#define NS 1024
#define NE 512
#define NA 64
#define NBH (NB*NH)

typedef short s8v __attribute__((ext_vector_type(8)));   // 8 bf16 (4 VGPRs)
typedef float f4v __attribute__((ext_vector_type(4)));   // 4 f32 accum

#define MFMA16(a,b,c) __builtin_amdgcn_mfma_f32_16x16x32_bf16((a),(b),(c),0,0,0)

static __device__ __forceinline__ unsigned short f2bf(float f) {
    union { float f; unsigned u; } c; c.f = f;
    unsigned r = c.u + 0x7FFF + ((c.u >> 16) & 1);   // RNE
    return (unsigned short)(r >> 16);
}
static __device__ __forceinline__ s8v ld8(const unsigned short* p) {
    return *(const s8v*)p;
}

// ---------------- K1: embedding gather + LayerNorm -> h_bf16 [B*S, E] ----------------
__global__ __launch_bounds__(256) void k_embed_ln(
    const int* __restrict__ x, const float* __restrict__ emb,
    const float* __restrict__ gamma, const float* __restrict__ beta,
    unsigned short* __restrict__ hb)
{
    int row = blockIdx.x;
    int tok = x[row];
    const float* e = emb + (size_t)tok * NE;
    int t = threadIdx.x;
    float v0 = e[t], v1 = e[t + 256];
    float sum = v0 + v1, ssq = v0 * v0 + v1 * v1;
    #pragma unroll
    for (int o = 32; o > 0; o >>= 1) {
        sum += __shfl_xor(sum, o);
        ssq += __shfl_xor(ssq, o);
    }
    __shared__ float wsum[4], wssq[4];
    __shared__ float mu_s, rstd_s;
    int wid = t >> 6;
    if ((t & 63) == 0) { wsum[wid] = sum; wssq[wid] = ssq; }
    __syncthreads();
    if (t == 0) {
        float S1 = wsum[0] + wsum[1] + wsum[2] + wsum[3];
        float S2 = wssq[0] + wssq[1] + wssq[2] + wssq[3];
        float mu = S1 / NE;
        float var = S2 / NE - mu * mu;
        mu_s = mu;
        rstd_s = rsqrtf(var + 1e-5f);
    }
    __syncthreads();
    float mu = mu_s, rstd = rstd_s;
    unsigned short* hr = hb + (size_t)row * NE;
    hr[t]       = f2bf((v0 - mu) * rstd * gamma[t]       + beta[t]);
    hr[t + 256] = f2bf((v1 - mu) * rstd * gamma[t + 256] + beta[t + 256]);
}

// ---------------- f32 -> bf16 convert ----------------
__global__ __launch_bounds__(256) void k_cvt(
    const float* __restrict__ in, unsigned short* __restrict__ out, int n)
{
    int i = blockIdx.x * 256 + threadIdx.x;
    if (i < n) out[i] = f2bf(in[i]);
}

// ---------------- K2: Q/K projection via MFMA -> q,k bf16 [bh][s][64] ----------------
// C[s][a] = sum_e h[s][e] * W[a][e]; A = h (row=s,k=e), B[k=e][col=a] = W row a.
__global__ __launch_bounds__(256, 4) void k_qk_mfma(
    const unsigned short* __restrict__ hb, const unsigned short* __restrict__ wqb,
    const unsigned short* __restrict__ wkb,
    unsigned short* __restrict__ qb, unsigned short* __restrict__ kbf)
{
    int bid = blockIdx.x;                       // 1024
    int b2 = (bid & 7) * 128 + (bid >> 3);      // bijective XCD swizzle
    int st = b2 & 15, bh = b2 >> 4;
    int b = bh >> 3, hh = bh & 7;
    int w = threadIdx.x >> 6, l = threadIdx.x & 63;
    int lo = l & 15, hi = l >> 4;
    int s0 = st * 64 + w * 16;

    f4v accq[4], acck[4];
    f4v z = {0.f, 0.f, 0.f, 0.f};
    #pragma unroll
    for (int cs = 0; cs < 4; ++cs) { accq[cs] = z; acck[cs] = z; }

    const unsigned short* hrow = hb + ((size_t)(b * NS) + s0 + lo) * NE + hi * 8;
    #pragma unroll 4
    for (int ks = 0; ks < 16; ++ks) {
        s8v a = ld8(hrow + ks * 32);
        #pragma unroll
        for (int cs = 0; cs < 4; ++cs) {
            s8v bq = ld8(wqb + ((size_t)(hh * NA) + cs * 16 + lo) * NE + ks * 32 + hi * 8);
            s8v bk = ld8(wkb + ((size_t)(hh * NA) + cs * 16 + lo) * NE + ks * 32 + hi * 8);
            accq[cs] = MFMA16(a, bq, accq[cs]);
            acck[cs] = MFMA16(a, bk, acck[cs]);
        }
    }
    #pragma unroll
    for (int cs = 0; cs < 4; ++cs)
        #pragma unroll
        for (int i = 0; i < 4; ++i) {
            size_t o = ((size_t)bh * NS + s0 + hi * 4 + i) * NA + cs * 16 + lo;
            qb[o] = f2bf(accq[cs][i]);
            kbf[o] = f2bf(acck[cs][i]);
        }
}

// ---------------- K3: V projection via MFMA -> vT bf16 [bh][e'][t] ----------------
// vT[e'][t] = sum_e Wv[e'][e] * h[t][e]; A = Wv (row=e',k=e), B[k=e][col=t] = h row t.
__global__ __launch_bounds__(256, 4) void k_v_mfma(
    const unsigned short* __restrict__ hb, const unsigned short* __restrict__ wvb,
    unsigned short* __restrict__ vtb)
{
    int bid = blockIdx.x;                       // 4096
    int b2 = (bid & 7) * 512 + (bid >> 3);
    int tt = b2 & 7;                            // t-tile of 128
    int et = (b2 >> 3) & 7;                     // e'-tile of 64
    int bh = b2 >> 6;
    int b = bh >> 3, hh = bh & 7;
    int w = threadIdx.x >> 6, l = threadIdx.x & 63;
    int lo = l & 15, hi = l >> 4;
    int e0 = et * 64 + w * 16;
    int t0 = tt * 128;

    f4v acc[8];
    f4v z = {0.f, 0.f, 0.f, 0.f};
    #pragma unroll
    for (int cs = 0; cs < 8; ++cs) acc[cs] = z;

    const unsigned short* wrow = wvb + ((size_t)(hh * NE) + e0 + lo) * NE + hi * 8;
    #pragma unroll 2
    for (int ks = 0; ks < 16; ++ks) {
        s8v a = ld8(wrow + ks * 32);
        #pragma unroll
        for (int cs = 0; cs < 8; ++cs) {
            s8v bv = ld8(hb + ((size_t)(b * NS) + t0 + cs * 16 + lo) * NE + ks * 32 + hi * 8);
            acc[cs] = MFMA16(a, bv, acc[cs]);
        }
    }
    #pragma unroll
    for (int cs = 0; cs < 8; ++cs)
        #pragma unroll
        for (int i = 0; i < 4; ++i)
            vtb[((size_t)bh * NE + e0 + hi * 4 + i) * NS + t0 + cs * 16 + lo] = f2bf(acc[cs][i]);
}

// ---------------- K4: per-row min/max of QK^T via MFMA ----------------
__global__ __launch_bounds__(256, 4) void k_minmax_mfma(
    const unsigned short* __restrict__ qb, const unsigned short* __restrict__ kbf,
    float* __restrict__ rmn, float* __restrict__ rmx)
{
    int bid = blockIdx.x;                       // 1024
    int b2 = (bid & 7) * 128 + (bid >> 3);
    int qt = b2 & 15, bh = b2 >> 4;
    int w = threadIdx.x >> 6, l = threadIdx.x & 63;
    int lo = l & 15, hi = l >> 4;
    int s0 = qt * 64 + w * 16;

    const unsigned short* qp = qb + ((size_t)bh * NS + s0 + lo) * NA + hi * 8;
    s8v a0 = ld8(qp), a1 = ld8(qp + 32);
    f4v mn4 = {1e30f, 1e30f, 1e30f, 1e30f};
    f4v mx4 = {-1e30f, -1e30f, -1e30f, -1e30f};
    for (int t0 = 0; t0 < NS; t0 += 16) {
        const unsigned short* kp = kbf + ((size_t)bh * NS + t0 + lo) * NA + hi * 8;
        f4v c = {0.f, 0.f, 0.f, 0.f};
        c = MFMA16(a0, ld8(kp), c);
        c = MFMA16(a1, ld8(kp + 32), c);
        #pragma unroll
        for (int i = 0; i < 4; ++i) {
            mn4[i] = fminf(mn4[i], c[i]);
            mx4[i] = fmaxf(mx4[i], c[i]);
        }
    }
    #pragma unroll
    for (int i = 0; i < 4; ++i) {
        float m = mn4[i], M = mx4[i];
        #pragma unroll
        for (int off = 1; off < 16; off <<= 1) {
            m = fminf(m, __shfl_xor(m, off));
            M = fmaxf(M, __shfl_xor(M, off));
        }
        if (lo == 0) {
            rmn[(size_t)bh * NS + s0 + hi * 4 + i] = m;
            rmx[(size_t)bh * NS + s0 + hi * 4 + i] = M;
        }
    }
}

// ---------------- K5: scores -> sigmoid weights -> PV, all MFMA ----------------
// block: 64 q-rows x full E, 8 waves (wave w: score cols t0+w*16, PV e-slice w*64)
#define WSTR 136   // wt LDS row stride (ushort): 272B = 17*16B -> aligned b128, 2-way banks
__global__ __launch_bounds__(512, 2) void k_attn_mfma(
    const unsigned short* __restrict__ qb, const unsigned short* __restrict__ kbf,
    const unsigned short* __restrict__ vtb, const float* __restrict__ rmn,
    const float* __restrict__ rmx, float* __restrict__ out)
{
    int bid = blockIdx.x;                       // 1024
    int b2 = (bid & 7) * 128 + (bid >> 3);
    int qt = b2 & 15, bh = b2 >> 4;
    int s0 = qt * 64;
    int tid = threadIdx.x;
    int w = tid >> 6, l = tid & 63;
    int lo = l & 15, hi = l >> 4;

    __shared__ unsigned short wt[64 * WSTR];    // 17408 B

    s8v qa[4][2];
    #pragma unroll
    for (int sub = 0; sub < 4; ++sub) {
        const unsigned short* p = qb + ((size_t)bh * NS + s0 + sub * 16 + lo) * NA + hi * 8;
        qa[sub][0] = ld8(p);
        qa[sub][1] = ld8(p + 32);
    }
    float mnv[4][4], invv[4][4];
    #pragma unroll
    for (int sub = 0; sub < 4; ++sub)
        #pragma unroll
        for (int i = 0; i < 4; ++i) {
            int r = s0 + sub * 16 + hi * 4 + i;
            float mn = rmn[(size_t)bh * NS + r];
            mnv[sub][i] = mn;
            invv[sub][i] = 1.f / (rmx[(size_t)bh * NS + r] - mn);
        }

    f4v acc[4][4];
    f4v z = {0.f, 0.f, 0.f, 0.f};
    #pragma unroll
    for (int sub = 0; sub < 4; ++sub)
        #pragma unroll
        for (int es = 0; es < 4; ++es) acc[sub][es] = z;

    for (int t0 = 0; t0 < NS; t0 += 128) {
        // --- QK^T for this wave's 16 t-cols ---
        int tc = t0 + w * 16;
        const unsigned short* kp = kbf + ((size_t)bh * NS + tc + lo) * NA + hi * 8;
        s8v kb0 = ld8(kp), kb1 = ld8(kp + 32);
        __syncthreads();   // prev iter's PV reads of wt are done
        #pragma unroll
        for (int sub = 0; sub < 4; ++sub) {
            f4v c = {0.f, 0.f, 0.f, 0.f};
            c = MFMA16(qa[sub][0], kb0, c);
            c = MFMA16(qa[sub][1], kb1, c);
            #pragma unroll
            for (int i = 0; i < 4; ++i) {
                float sn = (c[i] - mnv[sub][i]) * invv[sub][i];
                float wv = 1.f / (1.f + __expf(5.f - 10.f * sn));
                wt[(sub * 16 + hi * 4 + i) * WSTR + w * 16 + lo] = f2bf(wv);
            }
        }
        __syncthreads();   // wt ready
        // --- PV: out[64q x 64e per wave] += W(64x128) @ V(128x64) ---
        #pragma unroll
        for (int ks = 0; ks < 4; ++ks) {
            s8v aw[4];
            #pragma unroll
            for (int sub = 0; sub < 4; ++sub)
                aw[sub] = *(const s8v*)(wt + (sub * 16 + lo) * WSTR + ks * 32 + hi * 8);
            #pragma unroll
            for (int es = 0; es < 4; ++es) {
                s8v bv = ld8(vtb + ((size_t)bh * NE + w * 64 + es * 16 + lo) * NS
                                 + t0 + ks * 32 + hi * 8);
                #pragma unroll
                for (int sub = 0; sub < 4; ++sub)
                    acc[sub][es] = MFMA16(aw[sub], bv, acc[sub][es]);
            }
        }
    }
    #pragma unroll
    for (int sub = 0; sub < 4; ++sub)
        #pragma unroll
        for (int es = 0; es < 4; ++es)
            #pragma unroll
            for (int i = 0; i < 4; ++i)
                out[((size_t)bh * NS + s0 + sub * 16 + hi * 4 + i) * NE
                    + w * 64 + es * 16 + lo] = acc[sub][es][i];
}

extern "C" void kernel_launch(void* const* d_in, const int* in_sizes, int n_in,
                              void* d_out, int out_size, void* d_ws, size_t ws_size,
                              hipStream_t stream) {
    const int*   x     = (const int*)d_in[0];
    const float* emb   = (const float*)d_in[1];
    const float* gamma = (const float*)d_in[2];
    const float* beta  = (const float*)d_in[3];
    const float* Wq    = (const float*)d_in[4];
    const float* Wk    = (const float*)d_in[5];
    const float* Wv    = (const float*)d_in[6];
    float* out = (float*)d_out;

    unsigned short* p = (unsigned short*)d_ws;
    unsigned short* hb  = p;  p += (size_t)NB * NS * NE;    // 4M ush
    unsigned short* qb  = p;  p += (size_t)NBH * NS * NA;   // 4M
    unsigned short* kb  = p;  p += (size_t)NBH * NS * NA;   // 4M
    unsigned short* vtb = p;  p += (size_t)NBH * NS * NE;   // 32M
    unsigned short* wqb = p;  p += (size_t)NH * NA * NE;    // 256K
    unsigned short* wkb = p;  p += (size_t)NH * NA * NE;    // 256K
    unsigned short* wvb = p;  p += (size_t)NH * NE * NE;    // 2M
    float* rmn = (float*)p;                                 // even ushort count -> 4B aligned
    float* rmx = rmn + (size_t)NBH * NS;

    const int nqk = NH * NA * NE, nv = NH * NE * NE;
    k_cvt<<<(nqk + 255) / 256, 256, 0, stream>>>(Wq, wqb, nqk);
    k_cvt<<<(nqk + 255) / 256, 256, 0, stream>>>(Wk, wkb, nqk);
    k_cvt<<<(nv + 255) / 256, 256, 0, stream>>>(Wv, wvb, nv);
    k_embed_ln<<<NB * NS, 256, 0, stream>>>(x, emb, gamma, beta, hb);
    k_qk_mfma<<<1024, 256, 0, stream>>>(hb, wqb, wkb, qb, kb);
    k_v_mfma<<<4096, 256, 0, stream>>>(hb, wvb, vtb);
    k_minmax_mfma<<<1024, 256, 0, stream>>>(qb, kb, rmn, rmx);
    k_attn_mfma<<<1024, 512, 0, stream>>>(qb, kb, vtb, rmn, rmx, out);
}

// Round 3
// 305.722 us; speedup vs baseline: 26.9480x; 2.0266x over previous
//
#include <hip/hip_runtime.h>
#include <math.h>

#define NB 8
#define NH 8
#define NS 1024
#define NE 512
#define NA 64
#define NBH (NB*NH)

typedef short s8v __attribute__((ext_vector_type(8)));   // 8 bf16 (4 VGPRs)
typedef float f4v __attribute__((ext_vector_type(4)));   // 4 f32 accum

#define MFMA16(a,b,c) __builtin_amdgcn_mfma_f32_16x16x32_bf16((a),(b),(c),0,0,0)

static __device__ __forceinline__ unsigned short f2bf(float f) {
    union { float f; unsigned u; } c; c.f = f;
    unsigned r = c.u + 0x7FFF + ((c.u >> 16) & 1);   // RNE
    return (unsigned short)(r >> 16);
}
static __device__ __forceinline__ s8v ld8(const unsigned short* p) {
    return *(const s8v*)p;
}
static __device__ __forceinline__ void gload16(const unsigned short* g, unsigned short* l) {
    __builtin_amdgcn_global_load_lds(
        (const __attribute__((address_space(1))) unsigned char*)g,
        (__attribute__((address_space(3))) unsigned char*)l, 16, 0, 0);
}

// stage a 128-row x 64-ush tile (row stride `stride` ush) into 16KB of LDS, linear.
// 256 threads: wave w, call c -> chunk = w*4+c covers rows [chunk*8, chunk*8+8)
static __device__ __forceinline__ void stage_tile(
    const unsigned short* src, size_t stride, int k0,
    unsigned short* lds, int tid)
{
    int w = tid >> 6, l = tid & 63;
    #pragma unroll
    for (int c = 0; c < 4; ++c) {
        int chunk = w * 4 + c;
        int row = chunk * 8 + (l >> 3);
        gload16(src + (size_t)row * stride + k0 + (l & 7) * 8,
                lds + chunk * 512 + l * 8);
    }
}

// ---------------- K1: embedding gather + LayerNorm -> h_bf16 [B*S, E] ----------------
__global__ __launch_bounds__(256) void k_embed_ln(
    const int* __restrict__ x, const float* __restrict__ emb,
    const float* __restrict__ gamma, const float* __restrict__ beta,
    unsigned short* __restrict__ hb)
{
    int row = blockIdx.x;
    int tok = x[row];
    const float* e = emb + (size_t)tok * NE;
    int t = threadIdx.x;
    float v0 = e[t], v1 = e[t + 256];
    float sum = v0 + v1, ssq = v0 * v0 + v1 * v1;
    #pragma unroll
    for (int o = 32; o > 0; o >>= 1) {
        sum += __shfl_xor(sum, o);
        ssq += __shfl_xor(ssq, o);
    }
    __shared__ float wsum[4], wssq[4];
    __shared__ float mu_s, rstd_s;
    int wid = t >> 6;
    if ((t & 63) == 0) { wsum[wid] = sum; wssq[wid] = ssq; }
    __syncthreads();
    if (t == 0) {
        float S1 = wsum[0] + wsum[1] + wsum[2] + wsum[3];
        float S2 = wssq[0] + wssq[1] + wssq[2] + wssq[3];
        float mu = S1 / NE;
        float var = S2 / NE - mu * mu;
        mu_s = mu;
        rstd_s = rsqrtf(var + 1e-5f);
    }
    __syncthreads();
    float mu = mu_s, rstd = rstd_s;
    unsigned short* hr = hb + (size_t)row * NE;
    hr[t]       = f2bf((v0 - mu) * rstd * gamma[t]       + beta[t]);
    hr[t + 256] = f2bf((v1 - mu) * rstd * gamma[t + 256] + beta[t + 256]);
}

// ---------------- f32 -> bf16 convert ----------------
__global__ __launch_bounds__(256) void k_cvt(
    const float* __restrict__ in, unsigned short* __restrict__ out, int n)
{
    int i = blockIdx.x * 256 + threadIdx.x;
    if (i < n) out[i] = f2bf(in[i]);
}

// ---------------- K2: Q/K projection, LDS-staged GEMM ----------------
// per bh: C[s, {q|k}a] (1024 x 128), K=512. Tile 128x128, BK=64. 512 blocks.
__global__ __launch_bounds__(256) void k_qk_gemm(
    const unsigned short* __restrict__ hb, const unsigned short* __restrict__ wqb,
    const unsigned short* __restrict__ wkb,
    unsigned short* __restrict__ qb, unsigned short* __restrict__ kbf)
{
    int bid = blockIdx.x;
    int b2 = (bid & 7) * 64 + (bid >> 3);       // XCD swizzle (512 % 8 == 0)
    int st = b2 & 7, bh = b2 >> 3;
    int b = bh >> 3, hh = bh & 7;
    int tid = threadIdx.x;
    int w = tid >> 6, l = tid & 63;
    int lo = l & 15, hi = l >> 4;
    int wr = w >> 1, wc = w & 1;

    __shared__ __align__(16) unsigned short As[128 * 64];
    __shared__ __align__(16) unsigned short Bs[128 * 64];

    f4v acc[4][4];
    f4v z = {0.f, 0.f, 0.f, 0.f};
    #pragma unroll
    for (int i = 0; i < 4; ++i)
        #pragma unroll
        for (int j = 0; j < 4; ++j) acc[i][j] = z;

    const unsigned short* asrc = hb + ((size_t)(b * NS) + st * 128) * NE;
    for (int kt = 0; kt < 8; ++kt) {
        int k0 = kt * 64;
        stage_tile(asrc, NE, k0, As, tid);
        // B rows 0..63 = Wq[hh], 64..127 = Wk[hh]  (chunks 0-7 / 8-15)
        {
            #pragma unroll
            for (int c = 0; c < 4; ++c) {
                int chunk = w * 4 + c;
                int row = chunk * 8 + (l >> 3);
                const unsigned short* bsrc = (chunk < 8)
                    ? wqb + ((size_t)(hh * NA) + row) * NE
                    : wkb + ((size_t)(hh * NA) + row - 64) * NE;
                gload16(bsrc + k0 + (l & 7) * 8, Bs + chunk * 512 + l * 8);
            }
        }
        __syncthreads();
        #pragma unroll
        for (int ks = 0; ks < 2; ++ks) {
            s8v af[4], bf[4];
            #pragma unroll
            for (int sub = 0; sub < 4; ++sub)
                af[sub] = ld8(As + (wr * 64 + sub * 16 + lo) * 64 + ks * 32 + hi * 8);
            #pragma unroll
            for (int es = 0; es < 4; ++es)
                bf[es] = ld8(Bs + (wc * 64 + es * 16 + lo) * 64 + ks * 32 + hi * 8);
            #pragma unroll
            for (int sub = 0; sub < 4; ++sub)
                #pragma unroll
                for (int es = 0; es < 4; ++es)
                    acc[sub][es] = MFMA16(af[sub], bf[es], acc[sub][es]);
        }
        __syncthreads();
    }
    unsigned short* dst = (wc == 0) ? qb : kbf;
    #pragma unroll
    for (int sub = 0; sub < 4; ++sub)
        #pragma unroll
        for (int es = 0; es < 4; ++es)
            #pragma unroll
            for (int i = 0; i < 4; ++i) {
                int s = st * 128 + wr * 64 + sub * 16 + hi * 4 + i;
                int a = es * 16 + lo;
                dst[((size_t)bh * NS + s) * NA + a] = f2bf(acc[sub][es][i]);
            }
}

// ---------------- K3: V projection, LDS-staged GEMM -> vT bf16 [bh][e'][t] ----------------
// per bh: C[e', t] (512 x 1024) = Wv[h] @ h[b]^T, K=512. Tile 128x128. 2048 blocks.
__global__ __launch_bounds__(256) void k_v_gemm(
    const unsigned short* __restrict__ hb, const unsigned short* __restrict__ wvb,
    unsigned short* __restrict__ vtb)
{
    int bid = blockIdx.x;
    int b2 = (bid & 7) * 256 + (bid >> 3);      // XCD swizzle (2048 % 8 == 0)
    int tt = b2 & 7;                            // t-tile (N)
    int et = (b2 >> 3) & 3;                     // e'-tile (M)
    int bh = b2 >> 5;
    int b = bh >> 3, hh = bh & 7;
    int tid = threadIdx.x;
    int w = tid >> 6, l = tid & 63;
    int lo = l & 15, hi = l >> 4;
    int wr = w >> 1, wc = w & 1;

    __shared__ __align__(16) unsigned short As[128 * 64];
    __shared__ __align__(16) unsigned short Bs[128 * 64];

    f4v acc[4][4];
    f4v z = {0.f, 0.f, 0.f, 0.f};
    #pragma unroll
    for (int i = 0; i < 4; ++i)
        #pragma unroll
        for (int j = 0; j < 4; ++j) acc[i][j] = z;

    const unsigned short* asrc = wvb + ((size_t)(hh * NE) + et * 128) * NE;
    const unsigned short* bsrc = hb + ((size_t)(b * NS) + tt * 128) * NE;
    for (int kt = 0; kt < 8; ++kt) {
        int k0 = kt * 64;
        stage_tile(asrc, NE, k0, As, tid);
        stage_tile(bsrc, NE, k0, Bs, tid);
        __syncthreads();
        #pragma unroll
        for (int ks = 0; ks < 2; ++ks) {
            s8v af[4], bf[4];
            #pragma unroll
            for (int sub = 0; sub < 4; ++sub)
                af[sub] = ld8(As + (wr * 64 + sub * 16 + lo) * 64 + ks * 32 + hi * 8);
            #pragma unroll
            for (int es = 0; es < 4; ++es)
                bf[es] = ld8(Bs + (wc * 64 + es * 16 + lo) * 64 + ks * 32 + hi * 8);
            #pragma unroll
            for (int sub = 0; sub < 4; ++sub)
                #pragma unroll
                for (int es = 0; es < 4; ++es)
                    acc[sub][es] = MFMA16(af[sub], bf[es], acc[sub][es]);
        }
        __syncthreads();
    }
    #pragma unroll
    for (int sub = 0; sub < 4; ++sub)
        #pragma unroll
        for (int es = 0; es < 4; ++es)
            #pragma unroll
            for (int i = 0; i < 4; ++i) {
                int e_ = et * 128 + wr * 64 + sub * 16 + hi * 4 + i;
                int t_ = tt * 128 + wc * 64 + es * 16 + lo;
                vtb[((size_t)bh * NE + e_) * NS + t_] = f2bf(acc[sub][es][i]);
            }
}

// ---------------- K4: per-row min/max of QK^T, LDS-staged K ----------------
// block: 64 q-rows (4 waves x 16), all t in chunks of 128. 1024 blocks.
__global__ __launch_bounds__(256) void k_minmax_mfma(
    const unsigned short* __restrict__ qb, const unsigned short* __restrict__ kbf,
    float* __restrict__ rmn, float* __restrict__ rmx)
{
    int bid = blockIdx.x;
    int b2 = (bid & 7) * 128 + (bid >> 3);
    int qt = b2 & 15, bh = b2 >> 4;
    int tid = threadIdx.x;
    int w = tid >> 6, l = tid & 63;
    int lo = l & 15, hi = l >> 4;
    int s0 = qt * 64 + w * 16;

    const unsigned short* qp = qb + ((size_t)bh * NS + s0 + lo) * NA + hi * 8;
    s8v a0 = ld8(qp), a1 = ld8(qp + 32);

    __shared__ __align__(16) unsigned short Ks[128 * 64];   // 16 KiB

    f4v mn4 = {1e30f, 1e30f, 1e30f, 1e30f};
    f4v mx4 = {-1e30f, -1e30f, -1e30f, -1e30f};
    const unsigned short* ksrc = kbf + (size_t)bh * NS * NA;
    for (int t0 = 0; t0 < NS; t0 += 128) {
        __syncthreads();   // prev chunk reads done
        stage_tile(ksrc + (size_t)t0 * NA, NA, 0, Ks, tid);
        __syncthreads();   // staged
        #pragma unroll
        for (int tf = 0; tf < 8; ++tf) {
            s8v b0 = ld8(Ks + (tf * 16 + lo) * 64 + hi * 8);
            s8v b1 = ld8(Ks + (tf * 16 + lo) * 64 + 32 + hi * 8);
            f4v c = {0.f, 0.f, 0.f, 0.f};
            c = MFMA16(a0, b0, c);
            c = MFMA16(a1, b1, c);
            #pragma unroll
            for (int i = 0; i < 4; ++i) {
                mn4[i] = fminf(mn4[i], c[i]);
                mx4[i] = fmaxf(mx4[i], c[i]);
            }
        }
    }
    #pragma unroll
    for (int i = 0; i < 4; ++i) {
        float m = mn4[i], M = mx4[i];
        #pragma unroll
        for (int off = 1; off < 16; off <<= 1) {
            m = fminf(m, __shfl_xor(m, off));
            M = fmaxf(M, __shfl_xor(M, off));
        }
        if (lo == 0) {
            rmn[(size_t)bh * NS + s0 + hi * 4 + i] = m;
            rmx[(size_t)bh * NS + s0 + hi * 4 + i] = M;
        }
    }
}

// ---------------- K5: scores -> sigmoid weights -> PV, all MFMA ----------------
#define WSTR 136
__global__ __launch_bounds__(512, 2) void k_attn_mfma(
    const unsigned short* __restrict__ qb, const unsigned short* __restrict__ kbf,
    const unsigned short* __restrict__ vtb, const float* __restrict__ rmn,
    const float* __restrict__ rmx, float* __restrict__ out)
{
    int bid = blockIdx.x;
    int b2 = (bid & 7) * 128 + (bid >> 3);
    int qt = b2 & 15, bh = b2 >> 4;
    int s0 = qt * 64;
    int tid = threadIdx.x;
    int w = tid >> 6, l = tid & 63;
    int lo = l & 15, hi = l >> 4;

    __shared__ unsigned short wt[64 * WSTR];

    s8v qa[4][2];
    #pragma unroll
    for (int sub = 0; sub < 4; ++sub) {
        const unsigned short* p = qb + ((size_t)bh * NS + s0 + sub * 16 + lo) * NA + hi * 8;
        qa[sub][0] = ld8(p);
        qa[sub][1] = ld8(p + 32);
    }
    float mnv[4][4], invv[4][4];
    #pragma unroll
    for (int sub = 0; sub < 4; ++sub)
        #pragma unroll
        for (int i = 0; i < 4; ++i) {
            int r = s0 + sub * 16 + hi * 4 + i;
            float mn = rmn[(size_t)bh * NS + r];
            mnv[sub][i] = mn;
            invv[sub][i] = 1.f / (rmx[(size_t)bh * NS + r] - mn);
        }

    f4v acc[4][4];
    f4v z = {0.f, 0.f, 0.f, 0.f};
    #pragma unroll
    for (int sub = 0; sub < 4; ++sub)
        #pragma unroll
        for (int es = 0; es < 4; ++es) acc[sub][es] = z;

    for (int t0 = 0; t0 < NS; t0 += 128) {
        int tc = t0 + w * 16;
        const unsigned short* kp = kbf + ((size_t)bh * NS + tc + lo) * NA + hi * 8;
        s8v kb0 = ld8(kp), kb1 = ld8(kp + 32);
        __syncthreads();
        #pragma unroll
        for (int sub = 0; sub < 4; ++sub) {
            f4v c = {0.f, 0.f, 0.f, 0.f};
            c = MFMA16(qa[sub][0], kb0, c);
            c = MFMA16(qa[sub][1], kb1, c);
            #pragma unroll
            for (int i = 0; i < 4; ++i) {
                float sn = (c[i] - mnv[sub][i]) * invv[sub][i];
                float wv = 1.f / (1.f + __expf(5.f - 10.f * sn));
                wt[(sub * 16 + hi * 4 + i) * WSTR + w * 16 + lo] = f2bf(wv);
            }
        }
        __syncthreads();
        #pragma unroll
        for (int ks = 0; ks < 4; ++ks) {
            s8v aw[4];
            #pragma unroll
            for (int sub = 0; sub < 4; ++sub)
                aw[sub] = *(const s8v*)(wt + (sub * 16 + lo) * WSTR + ks * 32 + hi * 8);
            #pragma unroll
            for (int es = 0; es < 4; ++es) {
                s8v bv = ld8(vtb + ((size_t)bh * NE + w * 64 + es * 16 + lo) * NS
                                 + t0 + ks * 32 + hi * 8);
                #pragma unroll
                for (int sub = 0; sub < 4; ++sub)
                    acc[sub][es] = MFMA16(aw[sub], bv, acc[sub][es]);
            }
        }
    }
    #pragma unroll
    for (int sub = 0; sub < 4; ++sub)
        #pragma unroll
        for (int es = 0; es < 4; ++es)
            #pragma unroll
            for (int i = 0; i < 4; ++i)
                out[((size_t)bh * NS + s0 + sub * 16 + hi * 4 + i) * NE
                    + w * 64 + es * 16 + lo] = acc[sub][es][i];
}

extern "C" void kernel_launch(void* const* d_in, const int* in_sizes, int n_in,
                              void* d_out, int out_size, void* d_ws, size_t ws_size,
                              hipStream_t stream) {
    const int*   x     = (const int*)d_in[0];
    const float* emb   = (const float*)d_in[1];
    const float* gamma = (const float*)d_in[2];
    const float* beta  = (const float*)d_in[3];
    const float* Wq    = (const float*)d_in[4];
    const float* Wk    = (const float*)d_in[5];
    const float* Wv    = (const float*)d_in[6];
    float* out = (float*)d_out;

    unsigned short* p = (unsigned short*)d_ws;
    unsigned short* hb  = p;  p += (size_t)NB * NS * NE;
    unsigned short* qb  = p;  p += (size_t)NBH * NS * NA;
    unsigned short* kb  = p;  p += (size_t)NBH * NS * NA;
    unsigned short* vtb = p;  p += (size_t)NBH * NS * NE;
    unsigned short* wqb = p;  p += (size_t)NH * NA * NE;
    unsigned short* wkb = p;  p += (size_t)NH * NA * NE;
    unsigned short* wvb = p;  p += (size_t)NH * NE * NE;
    float* rmn = (float*)p;
    float* rmx = rmn + (size_t)NBH * NS;

    const int nqk = NH * NA * NE, nv = NH * NE * NE;
    k_cvt<<<(nqk + 255) / 256, 256, 0, stream>>>(Wq, wqb, nqk);
    k_cvt<<<(nqk + 255) / 256, 256, 0, stream>>>(Wk, wkb, nqk);
    k_cvt<<<(nv + 255) / 256, 256, 0, stream>>>(Wv, wvb, nv);
    k_embed_ln<<<NB * NS, 256, 0, stream>>>(x, emb, gamma, beta, hb);
    k_qk_gemm<<<512, 256, 0, stream>>>(hb, wqb, wkb, qb, kb);
    k_v_gemm<<<2048, 256, 0, stream>>>(hb, wvb, vtb);
    k_minmax_mfma<<<1024, 256, 0, stream>>>(qb, kb, rmn, rmx);
    k_attn_mfma<<<1024, 512, 0, stream>>>(qb, kb, vtb, rmn, rmx, out);
}